// Round 11
// baseline (896.326 us; speedup 1.0000x reference)
//
#include <hip/hip_runtime.h>
#include <hip/hip_bf16.h>

#define B_    2
#define SSRC  8192
#define TT    4096
#define NHN   16
#define NC    64
#define CS    128           // SSRC / NC
#define LOG100D 4.605170185988091368035982909368

typedef short s16x8 __attribute__((ext_vector_type(8)));
typedef float f32x4 __attribute__((ext_vector_type(4)));
typedef double f64x4 __attribute__((ext_vector_type(4)));
typedef unsigned long long u64;

typedef const __attribute__((address_space(1))) void* gas_ptr;
typedef __attribute__((address_space(3))) void* las_ptr;
#define GLDS16(g, l) __builtin_amdgcn_global_load_lds((gas_ptr)(g), (las_ptr)(l), 16, 0, 0)

// wave-local LDS fence: scratch is per-wave, no cross-wave barrier needed
#define WFENCE asm volatile("s_waitcnt lgkmcnt(0)" ::: "memory")

__device__ __forceinline__ unsigned short f2bf(float f) {
    unsigned u = __float_as_uint(f);
    u = u + 0x7fffu + ((u >> 16) & 1u);
    return (unsigned short)(u >> 16);
}
__device__ __forceinline__ float bf2f(unsigned short h) {
    return __uint_as_float(((unsigned)h) << 16);
}
__device__ __forceinline__ double lrelu_d(double v) { return v >= 0.0 ? v : 0.2 * v; }
__device__ __forceinline__ double gelu_d(double u) {
    double a = 0.7978845608028654 * (u + 0.044715 * u * u * u);
    return 0.5 * u * (1.0 + tanh(a));
}
__device__ __forceinline__ double rsum16d(double v) {
    v += __shfl_xor(v, 1); v += __shfl_xor(v, 2);
    v += __shfl_xor(v, 4); v += __shfl_xor(v, 8);
    return v;
}
__device__ __forceinline__ double rmax16d(double v) {
    v = fmax(v, __shfl_xor(v, 1)); v = fmax(v, __shfl_xor(v, 2));
    v = fmax(v, __shfl_xor(v, 4)); v = fmax(v, __shfl_xor(v, 8));
    return v;
}
__device__ __forceinline__ double rsum64d(double v) {
    v += __shfl_xor(v, 1); v += __shfl_xor(v, 2); v += __shfl_xor(v, 4);
    v += __shfl_xor(v, 8); v += __shfl_xor(v, 16); v += __shfl_xor(v, 32);
    return v;
}

// ---- f64 MFMA layout discovery: returns candidate 0..7 or -1 ----
// candidate c = (dm<<2)|(am<<1)|bm with
//   am: A lane map  0: l=i+16k   1: l=4i+k      (A is 16x4: X[i][k])
//   bm: B lane map  0: l=j+16k   1: l=4j+k      (B is 4x16: W[k][j])
//   dm: D placement 0: i=4*lg+r  1: i=lg+4r     (col j = l&15 in both)
__device__ __forceinline__ int mfma64_discover() {
    int lane = threadIdx.x & 63;
    int l15 = lane & 15, lg = lane >> 4;
    double va = (double)(1 + ((lane * 37) % 61));
    double vb = (double)(2 + ((lane * 53) % 59));
    f64x4 d = (f64x4){0.0, 0.0, 0.0, 0.0};
    d = __builtin_amdgcn_mfma_f64_16x16x4f64(va, vb, d, 0, 0, 0);
    int found = -1;
#pragma unroll
    for (int c = 0; c < 8; c++) {
        int dm = (c >> 2) & 1, am = (c >> 1) & 1, bm = c & 1;
        bool ok = true;
#pragma unroll
        for (int r = 0; r < 4; r++) {
            int i = dm ? (lg + 4 * r) : (4 * lg + r);
            int j = l15;
            double e = 0.0;
#pragma unroll
            for (int k = 0; k < 4; k++) {
                int la = am ? (4 * i + k) : (i + 16 * k);
                int lb = bm ? (4 * j + k) : (j + 16 * k);
                e += (double)(1 + ((la * 37) % 61)) * (double)(2 + ((lb * 53) % 59));
            }
            ok = ok && (d[r] == e);
        }
        if (__all(ok) && found < 0) found = c;
    }
    return found;   // wave-uniform, deterministic
}

// ---- branch-free 16-element sorting primitives (u64 keys, static reg indices) ----
__device__ __forceinline__ void ce(u64 &a, u64 &b) {
    bool c = a < b; u64 lo = c ? a : b; u64 hi = c ? b : a; a = lo; b = hi;
}
// Batcher merge-exchange sort, 63 CEs, ascending
__device__ __forceinline__ void sort16(u64 (&k)[16]) {
    ce(k[0],k[8]); ce(k[1],k[9]); ce(k[2],k[10]); ce(k[3],k[11]);
    ce(k[4],k[12]); ce(k[5],k[13]); ce(k[6],k[14]); ce(k[7],k[15]);
    ce(k[0],k[4]); ce(k[1],k[5]); ce(k[2],k[6]); ce(k[3],k[7]);
    ce(k[8],k[12]); ce(k[9],k[13]); ce(k[10],k[14]); ce(k[11],k[15]);
    ce(k[4],k[8]); ce(k[5],k[9]); ce(k[6],k[10]); ce(k[7],k[11]);
    ce(k[0],k[2]); ce(k[1],k[3]); ce(k[4],k[6]); ce(k[5],k[7]);
    ce(k[8],k[10]); ce(k[9],k[11]); ce(k[12],k[14]); ce(k[13],k[15]);
    ce(k[2],k[8]); ce(k[3],k[9]); ce(k[6],k[12]); ce(k[7],k[13]);
    ce(k[2],k[4]); ce(k[3],k[5]); ce(k[6],k[8]); ce(k[7],k[9]);
    ce(k[10],k[12]); ce(k[11],k[13]);
    ce(k[0],k[1]); ce(k[2],k[3]); ce(k[4],k[5]); ce(k[6],k[7]);
    ce(k[8],k[9]); ce(k[10],k[11]); ce(k[12],k[13]); ce(k[14],k[15]);
    ce(k[1],k[8]); ce(k[3],k[10]); ce(k[5],k[12]); ce(k[7],k[14]);
    ce(k[1],k[4]); ce(k[3],k[6]); ce(k[5],k[8]); ce(k[7],k[10]);
    ce(k[9],k[12]); ce(k[11],k[14]);
    ce(k[1],k[2]); ce(k[3],k[4]); ce(k[5],k[6]); ce(k[7],k[8]);
    ce(k[9],k[10]); ce(k[11],k[12]); ce(k[13],k[14]);
}
// bitonic merge of a unimodal 16-seq -> sorted asc, 32 CEs
__device__ __forceinline__ void bmerge16(u64 (&k)[16]) {
    ce(k[0],k[8]); ce(k[1],k[9]); ce(k[2],k[10]); ce(k[3],k[11]);
    ce(k[4],k[12]); ce(k[5],k[13]); ce(k[6],k[14]); ce(k[7],k[15]);
    ce(k[0],k[4]); ce(k[1],k[5]); ce(k[2],k[6]); ce(k[3],k[7]);
    ce(k[8],k[12]); ce(k[9],k[13]); ce(k[10],k[14]); ce(k[11],k[15]);
    ce(k[0],k[2]); ce(k[1],k[3]); ce(k[4],k[6]); ce(k[5],k[7]);
    ce(k[8],k[10]); ce(k[9],k[11]); ce(k[12],k[14]); ce(k[13],k[15]);
    ce(k[0],k[1]); ce(k[2],k[3]); ce(k[4],k[5]); ce(k[6],k[7]);
    ce(k[8],k[9]); ce(k[10],k[11]); ce(k[12],k[13]); ce(k[14],k[15]);
}
// keep 16 smallest of sorted L and sorted B (both asc); L out sorted asc
__device__ __forceinline__ void merge_keep16(u64 (&L)[16], const u64 (&B)[16]) {
#pragma unroll
    for (int i = 0; i < 16; i++) { u64 bb = B[15 - i]; L[i] = L[i] < bb ? L[i] : bb; }
    bmerge16(L);
}

// ---------------- top-k phase A: per-chunk sorted top-16 (batch-bitonic) ----------------
__global__ __launch_bounds__(256) void topk_partial(
    const float* __restrict__ c1, const float* __restrict__ c2,
    u64* __restrict__ cand)
{
    int t = blockIdx.x * 256 + threadIdx.x;
    int ch = blockIdx.y, b = blockIdx.z;
    const float* p1 = c1 + ((size_t)b * SSRC + (size_t)ch * CS) * TT + t;
    const float* p2 = c2 + ((size_t)b * SSRC + (size_t)ch * CS) * TT + t;
    u64 k[16];
#pragma unroll
    for (int j = 0; j < 16; j++) k[j] = ~0ull;
    int sbase = ch * CS;
    for (int s = 0; s < CS; s += 16) {
        u64 bt[16];
#pragma unroll
        for (int u = 0; u < 16; u++) {
            float a_ = p1[(size_t)(s + u) * TT];
            float b_ = p2[(size_t)(s + u) * TT];
            // exact IEEE mul/add to match numpy f32 (no fma contraction)
            float dd = __fadd_rn(__fmul_rn(a_, a_), __fmul_rn(b_, b_));
            bt[u] = ((u64)__float_as_uint(dd) << 32) | (unsigned)(sbase + s + u);
        }
        sort16(bt);
        merge_keep16(k, bt);
    }
    u64* dst = cand + ((size_t)(b * NC + ch) * 16) * TT + t;
#pragma unroll
    for (int j = 0; j < 16; j++) dst[(size_t)j * TT] = k[j];
}

// ---------------- top-k merge level 1: 64 chunk-lists -> 8 group-lists ----------------
__global__ __launch_bounds__(64) void topk_merge1(
    const u64* __restrict__ cand, u64* __restrict__ c2c)
{
    int t = blockIdx.x * 64 + threadIdx.x;
    int g = blockIdx.y, b = blockIdx.z;
    u64 k[16];
#pragma unroll
    for (int j = 0; j < 16; j++) k[j] = ~0ull;
    for (int c = g * 8; c < g * 8 + 8; c++) {
        const u64* src = cand + ((size_t)(b * NC + c) * 16) * TT + t;
        u64 bt[16];
#pragma unroll
        for (int j = 0; j < 16; j++) bt[j] = src[(size_t)j * TT];
        merge_keep16(k, bt);
    }
    u64* dst = c2c + ((size_t)((b * 8 + g) * 16)) * TT + t;
#pragma unroll
    for (int j = 0; j < 16; j++) dst[(size_t)j * TT] = k[j];
}

// ---------------- top-k merge level 2: 8 lists -> sorted knn indices ----------------
__global__ __launch_bounds__(64) void topk_merge2(
    const u64* __restrict__ c2c, int* __restrict__ knn)
{
    int t = blockIdx.x * 64 + threadIdx.x;
    int b = blockIdx.y;
    u64 k[16];
#pragma unroll
    for (int j = 0; j < 16; j++) k[j] = ~0ull;
    for (int c = 0; c < 8; c++) {
        const u64* src = c2c + ((size_t)(b * 8 + c) * 16) * TT + t;
        u64 bt[16];
#pragma unroll
        for (int j = 0; j < 16; j++) bt[j] = src[(size_t)j * TT];
        merge_keep16(k, bt);
    }
#pragma unroll
    for (int j = 0; j < 16; j++)
        knn[((size_t)b * TT + t) * 16 + j] = (int)(unsigned)(k[j] & 0xffffffffull);
}

// ------- weight transpose + split-bf16 convert (mu_W1/mu_W2 -> W^T hi/lo) -------
__global__ __launch_bounds__(256) void wconv(
    const float* __restrict__ Wa, const float* __restrict__ Wb,
    unsigned short* __restrict__ Oah, unsigned short* __restrict__ Oal,
    unsigned short* __restrict__ Obh, unsigned short* __restrict__ Obl)
{
    const float* W = blockIdx.z ? Wb : Wa;
    unsigned short* Oh = blockIdx.z ? Obh : Oah;
    unsigned short* Ol = blockIdx.z ? Obl : Oal;
    __shared__ float tile[64][65];
    int tx = threadIdx.x & 63, ty = threadIdx.x >> 6;
    int n0 = blockIdx.x * 64, k0 = blockIdx.y * 64;
#pragma unroll
    for (int r = ty; r < 64; r += 4) tile[r][tx] = W[(size_t)(k0 + r) * 1024 + n0 + tx];
    __syncthreads();
#pragma unroll
    for (int r = ty; r < 64; r += 4) {
        float v = tile[tx][r];
        unsigned short hi = f2bf(v);
        Oh[(size_t)(n0 + r) * 1024 + k0 + tx] = hi;
        Ol[(size_t)(n0 + r) * 1024 + k0 + tx] = f2bf(v - bf2f(hi));
    }
}

// ============ stage A (MFMA variant): gather + PE MLP + LN1 -> h ============
// peW2 read from GLOBAL (L1/L2-served; same f32 values as LDS staging)
__global__ __launch_bounds__(256) void tok_pe_m(
    const float* __restrict__ x, const float* __restrict__ c1, const float* __restrict__ c2,
    const int* __restrict__ knn,
    const float* __restrict__ peW1, const float* __restrict__ peb1,
    const float* __restrict__ peW2, const float* __restrict__ peb2,
    const float* __restrict__ g1, const float* __restrict__ be1,
    float* __restrict__ hout)
{
    int cand = mfma64_discover();
    if (cand < 0) return;   // block-uniform
    __shared__ float s_peW1[256], s_peb1[128], s_peb2[64], s_g1[64], s_be1[64];
    __shared__ float s_scr[4][2352];
    int tid = threadIdx.x, lane = tid & 63, w = tid >> 6;
    if (tid < 256) s_peW1[tid] = peW1[tid];
    if (tid < 128) s_peb1[tid] = peb1[tid];
    if (tid < 64) { s_peb2[tid] = peb2[tid]; s_g1[tid] = g1[tid]; s_be1[tid] = be1[tid]; }
    __syncthreads();

    int l15 = lane & 15, lg = lane >> 4;
    int am = (cand >> 1) & 1, bm = cand & 1, dm = (cand >> 2) & 1;
    int a_i = am ? (lane >> 2) : l15;
    int a_k = am ? (lane & 3)  : lg;
    int b_k = bm ? (lane & 3)  : lg;
    int b_j = bm ? (lane >> 2) : l15;
    int i0 = dm ? lg : 4 * lg;
    int istep = dm ? 4 : 1;

    float* big = s_scr[w];
    float* sc1 = big + 2304; float* sc2 = big + 2320; float* sx = big + 2336;
    double w0a = s_peW1[lane], w1a = s_peW1[128 + lane], ba = s_peb1[lane];
    double w0b = s_peW1[64 + lane], w1b = s_peW1[192 + lane], bbv = s_peb1[64 + lane];
    double g1v[4], be1v[4], pb2v[4];
#pragma unroll
    for (int j = 0; j < 4; j++) {
        g1v[j]  = (double)s_g1[j * 16 + l15];
        be1v[j] = (double)s_be1[j * 16 + l15];
        pb2v[j] = (double)s_peb2[j * 16 + l15];
    }

    for (int it = 0; it < 4; ++it) {
        int tk = blockIdx.x * 16 + w * 4 + it;
        int bb = tk >> 12, tt = tk & (TT - 1);
        if (lane < 16) {
            int s = knn[(size_t)tk * 16 + lane];
            sc1[lane] = c1[((size_t)bb * SSRC + s) * TT + tt];
            sc2[lane] = c2[((size_t)bb * SSRC + s) * TT + tt];
            sx[lane]  = x[bb * SSRC + s];
        }
        WFENCE;
#pragma unroll
        for (int n = 0; n < 16; n++) {
            double a_ = (double)sc1[n], b_ = (double)sc2[n];
            big[lane * 18 + n]        = (float)gelu_d(a_ * w0a + b_ * w1a + ba);
            big[(lane + 64) * 18 + n] = (float)gelu_d(a_ * w0b + b_ * w1b + bbv);
        }
        WFENCE;
        // PE2 via f64 MFMA (discovered layout): OUT[n][e] = gT^T @ W2
        f64x4 acc[4];
#pragma unroll
        for (int j = 0; j < 4; j++) acc[j] = (f64x4){0.0, 0.0, 0.0, 0.0};
        for (int ks = 0; ks < 32; ks++) {
            double a = (double)big[(4 * ks + a_k) * 18 + a_i];
            const float* wrow = peW2 + (4 * ks + b_k) * 64 + b_j;
#pragma unroll
            for (int j = 0; j < 4; j++)
                acc[j] = __builtin_amdgcn_mfma_f64_16x16x4f64(a, (double)wrow[j * 16], acc[j], 0, 0, 0);
        }
        float* op = hout + (size_t)tk * 1024;
#pragma unroll
        for (int r = 0; r < 4; r++) {
            int n = i0 + istep * r;
            double xr = (double)sx[n];
            double v[4], s = 0.0;
#pragma unroll
            for (int j = 0; j < 4; j++) { v[j] = acc[j][r] + pb2v[j] + xr; s += v[j]; }
            double m = rsum16d(s) * (1.0 / 64.0);
            double q = 0.0;
#pragma unroll
            for (int j = 0; j < 4; j++) { double d = v[j] - m; q += d * d; }
            double var = rsum16d(q) * (1.0 / 64.0);
            double rs = sqrt(var + 1e-5);
#pragma unroll
            for (int j = 0; j < 4; j++)
                op[n * 64 + j * 16 + l15] = (float)((v[j] - m) / rs * g1v[j] + be1v[j]);
        }
    }
}

// ============ stage A (VALU variant, round-7 numerics; peW2 global) ============
__global__ __launch_bounds__(256) void tok_pe_v(
    const float* __restrict__ x, const float* __restrict__ c1, const float* __restrict__ c2,
    const int* __restrict__ knn,
    const float* __restrict__ peW1, const float* __restrict__ peb1,
    const float* __restrict__ peW2, const float* __restrict__ peb2,
    const float* __restrict__ g1, const float* __restrict__ be1,
    float* __restrict__ hout)
{
    int cand = mfma64_discover();
    if (cand >= 0) return;
    __shared__ float s_peW1[256], s_peb1[128], s_peb2[64], s_g1[64], s_be1[64];
    __shared__ float s_scr[4][2352];
    int tid = threadIdx.x, lane = tid & 63, w = tid >> 6;
    if (tid < 256) s_peW1[tid] = peW1[tid];
    if (tid < 128) s_peb1[tid] = peb1[tid];
    if (tid < 64) { s_peb2[tid] = peb2[tid]; s_g1[tid] = g1[tid]; s_be1[tid] = be1[tid]; }
    __syncthreads();

    float* big = s_scr[w];
    float* sc1 = big + 2304; float* sc2 = big + 2320; float* sx = big + 2336;
    double w0a = s_peW1[lane], w1a = s_peW1[128 + lane], ba = s_peb1[lane];
    double w0b = s_peW1[64 + lane], w1b = s_peW1[192 + lane], bbv = s_peb1[64 + lane];
    double gv = (double)s_g1[lane], bv = (double)s_be1[lane];
    double pb2 = (double)s_peb2[lane];

    for (int it = 0; it < 4; ++it) {
        int tk = blockIdx.x * 16 + w * 4 + it;
        int bb = tk >> 12, tt = tk & (TT - 1);
        if (lane < 16) {
            int s = knn[(size_t)tk * 16 + lane];
            sc1[lane] = c1[((size_t)bb * SSRC + s) * TT + tt];
            sc2[lane] = c2[((size_t)bb * SSRC + s) * TT + tt];
            sx[lane]  = x[bb * SSRC + s];
        }
        WFENCE;
#pragma unroll
        for (int n = 0; n < 16; n++) {
            double a_ = (double)sc1[n], b_ = (double)sc2[n];
            big[lane * 18 + n]        = (float)gelu_d(a_ * w0a + b_ * w1a + ba);
            big[(lane + 64) * 18 + n] = (float)gelu_d(a_ * w0b + b_ * w1b + bbv);
        }
        WFENCE;
        double acc[16];
#pragma unroll
        for (int n = 0; n < 16; n++) acc[n] = pb2;
        for (int f = 0; f < 128; f++) {
            double wv = (double)peW2[f * 64 + lane];
#pragma unroll
            for (int n = 0; n < 16; n += 2) {
                float2 gvv = *(const float2*)&big[f * 18 + n];
                acc[n]     += (double)gvv.x * wv;
                acc[n + 1] += (double)gvv.y * wv;
            }
        }
        float* op = hout + (size_t)tk * 1024 + lane;
#pragma unroll
        for (int n = 0; n < 16; n++) {
            double v = acc[n] + (double)sx[n];
            double m = rsum64d(v) * (1.0 / 64.0);
            double d = v - m;
            double var = rsum64d(d * d) * (1.0 / 64.0);
            op[n * 64] = (float)(d / sqrt(var + 1e-5) * gv + bv);
        }
    }
}

// ============ stage B: q/k VALU (Wq/Wk global) + cosine attn + WoV + LN2 ============
__global__ __launch_bounds__(256) void tok_attn(
    const float* __restrict__ x, const int* __restrict__ knn,
    const float* __restrict__ Wq, const float* __restrict__ Wk,
    const float* __restrict__ Wv, const float* __restrict__ lsc,
    const float* __restrict__ Wo, const float* __restrict__ bo,
    const float* __restrict__ g2, const float* __restrict__ be2,
    float* __restrict__ hio)
{
    __shared__ float s_WoV[256], s_bo[64], s_g2[64], s_be2[64];
    __shared__ float s_scr[4][2320];
    int tid = threadIdx.x, lane = tid & 63, w = tid >> 6;
    if (tid < 64) {
        s_bo[tid] = bo[tid]; s_g2[tid] = g2[tid]; s_be2[tid] = be2[tid];
        for (int hh = 0; hh < 4; hh++) {
            double a = 0.0;
            for (int hd = 0; hd < 16; hd++)
                a += (double)Wv[hh * 16 + hd] * (double)Wo[(hh * 16 + hd) * 64 + tid];
            s_WoV[hh * 64 + tid] = (float)a;
        }
    }
    __syncthreads();

    int head = lane >> 4, mm = lane & 15;
    double scaleh = exp(fmin((double)lsc[head], LOG100D));
    double wov0 = (double)s_WoV[lane], wov1 = (double)s_WoV[64 + lane];
    double wov2 = (double)s_WoV[128 + lane], wov3 = (double)s_WoV[192 + lane];
    double gv = (double)s_g2[lane], bv = (double)s_be2[lane], bov = (double)s_bo[lane];
    float* big = s_scr[w];
    float* sx = big + 2304;

    for (int it = 0; it < 4; ++it) {
        int tk = blockIdx.x * 16 + w * 4 + it;
        int bb = tk >> 12;
        if (lane < 16) {
            int s = knn[(size_t)tk * 16 + lane];
            sx[lane] = x[bb * SSRC + s];
        }
        float* hp = hio + (size_t)tk * 1024 + lane;
        double h[16];
#pragma unroll
        for (int n = 0; n < 16; n++) {
            h[n] = (double)hp[n * 64];
            big[lane * 18 + n] = (float)h[n];   // hT[k=lane][n]
        }
        WFENCE;
        // q = h@Wq, k = h@Wk (f64; weights from global, L1-served)
        double q[16], k2[16];
#pragma unroll
        for (int n = 0; n < 16; n++) { q[n] = 0.0; k2[n] = 0.0; }
        for (int kk = 0; kk < 64; kk++) {
            double wq = (double)Wq[kk * 64 + lane], wk = (double)Wk[kk * 64 + lane];
#pragma unroll
            for (int n = 0; n < 16; n += 2) {
                float2 hv = *(const float2*)&big[kk * 18 + n];
                q[n]  += (double)hv.x * wq; q[n + 1]  += (double)hv.y * wq;
                k2[n] += (double)hv.x * wk; k2[n + 1] += (double)hv.y * wk;
            }
        }
#pragma unroll
        for (int n = 0; n < 16; n++) {
            double sq = rsum16d(q[n] * q[n]);   q[n]  /= sqrt(sq + 1e-12);
            double sk = rsum16d(k2[n] * k2[n]); k2[n] /= sqrt(sk + 1e-12);
        }
        WFENCE;   // ensure hT reads retired before overwrite
#pragma unroll
        for (int n = 0; n < 16; n++) {
            big[lane * 18 + n]        = (float)q[n];
            big[1152 + lane * 18 + n] = (float)k2[n];
        }
        WFENCE;
        // S = qn@kn^T * scale, softmax, A = att @ x
        double A_[16];
        {
            double S[16];
#pragma unroll
            for (int n = 0; n < 16; n++) S[n] = 0.0;
            for (int hd = 0; hd < 16; hd++) {
                int r = head * 16 + hd;
                double kf = (double)big[1152 + r * 18 + mm];
#pragma unroll
                for (int n = 0; n < 16; n += 2) {
                    float2 qq = *(const float2*)&big[r * 18 + n];
                    S[n] += (double)qq.x * kf; S[n + 1] += (double)qq.y * kf;
                }
            }
            double xv = (double)sx[mm];
#pragma unroll
            for (int n = 0; n < 16; n++) {
                double sv = S[n] * scaleh;
                double mx = rmax16d(sv);
                double e = exp(sv - mx);
                double se = rsum16d(e);
                A_[n] = rsum16d((e / se) * xv);
            }
        }
#pragma unroll
        for (int n = 0; n < 16; n++) {
            double a0 = __shfl(A_[n], mm), a1 = __shfl(A_[n], 16 + mm);
            double a2 = __shfl(A_[n], 32 + mm), a3 = __shfl(A_[n], 48 + mm);
            double v = h[n] + a0 * wov0 + a1 * wov1 + a2 * wov2 + a3 * wov3 + bov;
            double m = rsum64d(v) * (1.0 / 64.0);
            double d = v - m;
            double var = rsum64d(d * d) * (1.0 / 64.0);
            hp[n * 64] = (float)(d / sqrt(var + 1e-5) * gv + bv);
        }
    }
}

// ============ stage C (MFMA variant): mnh MLP + LN3 -> hn split-bf16 (mW1 global) ============
__global__ __launch_bounds__(256) void tok_mnh_m(
    const float* __restrict__ hin,
    const float* __restrict__ mW1, const float* __restrict__ mb1,
    const float* __restrict__ mW2, const float* __restrict__ mb2,
    const float* __restrict__ g3, const float* __restrict__ be3,
    unsigned short* __restrict__ hnh, unsigned short* __restrict__ hnl)
{
    int cand = mfma64_discover();
    if (cand < 0) return;
    __shared__ float s_mb1[128], s_mW2[128], s_g3[1024], s_be3[1024];
    __shared__ float s_scr[4][1152];
    int tid = threadIdx.x, lane = tid & 63, w = tid >> 6;
    if (tid < 128) { s_mb1[tid] = mb1[tid]; s_mW2[tid] = mW2[tid]; }
    for (int i = tid; i < 1024; i += 256) { s_g3[i] = g3[i]; s_be3[i] = be3[i]; }
    __syncthreads();

    int l15 = lane & 15, lg = lane >> 4;
    int am = (cand >> 1) & 1, bm = cand & 1, dm = (cand >> 2) & 1;
    int a_i = am ? (lane >> 2) : l15;
    int a_k = am ? (lane & 3)  : lg;
    int b_k = bm ? (lane & 3)  : lg;
    int b_j = bm ? (lane >> 2) : l15;

    double mb2s = (double)mb2[0];
    double mb1v[8], w2v[8];
#pragma unroll
    for (int j = 0; j < 8; j++) {
        mb1v[j] = (double)s_mb1[j * 16 + l15];
        w2v[j]  = (double)s_mW2[j * 16 + l15];
    }
    float* big = s_scr[w];

    for (int it = 0; it < 4; ++it) {
        int tk = blockIdx.x * 16 + w * 4 + it;
        const float* hp = hin + (size_t)tk * 1024 + lane;
        double h[16];
#pragma unroll
        for (int n = 0; n < 16; n++) {
            h[n] = (double)hp[n * 64];
            big[lane * 18 + n] = (float)h[n];
        }
        WFENCE;
        f64x4 acc[8];
#pragma unroll
        for (int j = 0; j < 8; j++) acc[j] = (f64x4){0.0, 0.0, 0.0, 0.0};
        for (int ks = 0; ks < 16; ks++) {
            double a = (double)big[(4 * ks + a_k) * 18 + a_i];
            const float* wrow = mW1 + (4 * ks + b_k) * 128 + b_j;
#pragma unroll
            for (int j = 0; j < 8; j++)
                acc[j] = __builtin_amdgcn_mfma_f64_16x16x4f64(a, (double)wrow[j * 16], acc[j], 0, 0, 0);
        }
        double p[4];
#pragma unroll
        for (int r = 0; r < 4; r++) {
            double s = 0.0;
#pragma unroll
            for (int j = 0; j < 8; j++) {
                double t = acc[j][r] + mb1v[j];
                s += lrelu_d(t) * w2v[j];
            }
            p[r] = rsum16d(s);
        }
        // broadcast p (lane group owning row n -> all lanes)
        if (dm == 0) {
#pragma unroll
            for (int n = 0; n < 16; n++) {
                double pn = __shfl(p[n & 3], (n >> 2) * 16);
                h[n] += lrelu_d(pn + mb2s);
            }
        } else {
#pragma unroll
            for (int n = 0; n < 16; n++) {
                double pn = __shfl(p[n >> 2], (n & 3) * 16);
                h[n] += lrelu_d(pn + mb2s);
            }
        }
        double s1 = 0.0;
#pragma unroll
        for (int n = 0; n < 16; n++) s1 += h[n];
        s1 = rsum64d(s1) * (1.0 / 1024.0);
        double s2v = 0.0;
#pragma unroll
        for (int n = 0; n < 16; n++) { double d = h[n] - s1; s2v += d * d; }
        s2v = rsum64d(s2v) * (1.0 / 1024.0);
        double rs = 1.0 / sqrt(s2v + 1e-5);
        unsigned short* oph = hnh + (size_t)tk * 1024 + lane;
        unsigned short* opl = hnl + (size_t)tk * 1024 + lane;
#pragma unroll
        for (int n = 0; n < 16; n++) {
            double v = (h[n] - s1) * rs * (double)s_g3[n * 64 + lane] + (double)s_be3[n * 64 + lane];
            unsigned short hi = f2bf((float)v);
            oph[n * 64] = hi;
            opl[n * 64] = f2bf((float)(v - (double)bf2f(hi)));
        }
    }
}

// ============ stage C (VALU variant, round-7 numerics; mW1 global) ============
__global__ __launch_bounds__(256) void tok_mnh_v(
    const float* __restrict__ hin,
    const float* __restrict__ mW1, const float* __restrict__ mb1,
    const float* __restrict__ mW2, const float* __restrict__ mb2,
    const float* __restrict__ g3, const float* __restrict__ be3,
    unsigned short* __restrict__ hnh, unsigned short* __restrict__ hnl)
{
    int cand = mfma64_discover();
    if (cand >= 0) return;
    __shared__ float s_mb1[128], s_mW2[128], s_g3[1024], s_be3[1024];
    __shared__ float s_scr[4][1152];
    int tid = threadIdx.x, lane = tid & 63, w = tid >> 6;
    if (tid < 128) { s_mb1[tid] = mb1[tid]; s_mW2[tid] = mW2[tid]; }
    for (int i = tid; i < 1024; i += 256) { s_g3[i] = g3[i]; s_be3[i] = be3[i]; }
    __syncthreads();

    double mb2s = (double)mb2[0];
    double mb1a = (double)s_mb1[lane], mb1b = (double)s_mb1[64 + lane];
    double w2a = (double)s_mW2[lane], w2b = (double)s_mW2[64 + lane];
    float* big = s_scr[w];

    for (int it = 0; it < 4; ++it) {
        int tk = blockIdx.x * 16 + w * 4 + it;
        const float* hp = hin + (size_t)tk * 1024 + lane;
        double h[16];
#pragma unroll
        for (int n = 0; n < 16; n++) {
            h[n] = (double)hp[n * 64];
            big[lane * 18 + n] = (float)h[n];
        }
        WFENCE;
        double t1a[16], t1b[16];
#pragma unroll
        for (int n = 0; n < 16; n++) { t1a[n] = mb1a; t1b[n] = mb1b; }
        for (int kk = 0; kk < 64; kk++) {
            double wa = (double)mW1[kk * 128 + lane], wb = (double)mW1[kk * 128 + 64 + lane];
#pragma unroll
            for (int n = 0; n < 16; n += 2) {
                float2 hv = *(const float2*)&big[kk * 18 + n];
                t1a[n] += (double)hv.x * wa; t1a[n + 1] += (double)hv.y * wa;
                t1b[n] += (double)hv.x * wb; t1b[n + 1] += (double)hv.y * wb;
            }
        }
#pragma unroll
        for (int n = 0; n < 16; n++) {
            double p = lrelu_d(t1a[n]) * w2a + lrelu_d(t1b[n]) * w2b;
            p = rsum64d(p);
            h[n] += lrelu_d(p + mb2s);
        }
        double s1 = 0.0;
#pragma unroll
        for (int n = 0; n < 16; n++) s1 += h[n];
        s1 = rsum64d(s1) * (1.0 / 1024.0);
        double s2v = 0.0;
#pragma unroll
        for (int n = 0; n < 16; n++) { double d = h[n] - s1; s2v += d * d; }
        s2v = rsum64d(s2v) * (1.0 / 1024.0);
        double rs = 1.0 / sqrt(s2v + 1e-5);
        unsigned short* oph = hnh + (size_t)tk * 1024 + lane;
        unsigned short* opl = hnl + (size_t)tk * 1024 + lane;
#pragma unroll
        for (int n = 0; n < 16; n++) {
            double v = (h[n] - s1) * rs * (double)s_g3[n * 64 + lane] + (double)s_be3[n * 64 + lane];
            unsigned short hi = f2bf((float)v);
            oph[n * 64] = hi;
            opl[n * 64] = f2bf((float)(v - (double)bf2f(hi)));
        }
    }
}

// ------- split-bf16 MFMA GEMM: out = lrelu(A@B + bias), A=Ah+Al, B=Bh+Bl -------
#define AH_OFF 0
#define AL_OFF 4096
#define BH_OFF 8192
#define BL_OFF 12288
template<int OUTSPLIT>
__global__ __launch_bounds__(256) void gemm_split(
    const unsigned short* __restrict__ Ah, const unsigned short* __restrict__ Al,
    const unsigned short* __restrict__ Bh, const unsigned short* __restrict__ Bl,
    const float* __restrict__ bias,
    unsigned short* __restrict__ oh, unsigned short* __restrict__ ol,
    float* __restrict__ of, int M, int N, int K)
{
    __shared__ unsigned short SM[16384];
    int tid = threadIdx.x, lane = tid & 63, w = tid >> 6;
    int wm = w >> 1, wn = w & 1;
    int m0 = blockIdx.y * 128, n0 = blockIdx.x * 128;
    f32x4 acc[4][4];
#pragma unroll
    for (int i = 0; i < 4; i++)
#pragma unroll
        for (int j = 0; j < 4; j++) acc[i][j] = (f32x4){0.f, 0.f, 0.f, 0.f};
    int row = tid >> 2, c8 = (tid & 3) * 8;
    size_t aoff = (size_t)(m0 + row) * K + c8;
    size_t boff = (size_t)(n0 + row) * K + c8;
    for (int kk = 0; kk < K; kk += 32) {
        __syncthreads();
        GLDS16(Ah + aoff + kk,                   SM + AH_OFF + tid * 8);
        GLDS16(Ah + aoff + (size_t)64 * K + kk,  SM + AH_OFF + 2048 + tid * 8);
        GLDS16(Al + aoff + kk,                   SM + AL_OFF + tid * 8);
        GLDS16(Al + aoff + (size_t)64 * K + kk,  SM + AL_OFF + 2048 + tid * 8);
        GLDS16(Bh + boff + kk,                   SM + BH_OFF + tid * 8);
        GLDS16(Bh + boff + (size_t)64 * K + kk,  SM + BH_OFF + 2048 + tid * 8);
        GLDS16(Bl + boff + kk,                   SM + BL_OFF + tid * 8);
        GLDS16(Bl + boff + (size_t)64 * K + kk,  SM + BL_OFF + 2048 + tid * 8);
        asm volatile("s_waitcnt vmcnt(0)" ::: "memory");
        __syncthreads();
        int kh = (lane >> 4) * 8, rA = wm * 64 + (lane & 15), rB = wn * 64 + (lane & 15);
        s16x8 afh[4], afl[4], bfh[4], bfl[4];
#pragma unroll
        for (int i = 0; i < 4; i++) {
            afh[i] = *(const s16x8*)&SM[AH_OFF + (rA + i * 16) * 32 + kh];
            afl[i] = *(const s16x8*)&SM[AL_OFF + (rA + i * 16) * 32 + kh];
            bfh[i] = *(const s16x8*)&SM[BH_OFF + (rB + i * 16) * 32 + kh];
            bfl[i] = *(const s16x8*)&SM[BL_OFF + (rB + i * 16) * 32 + kh];
        }
#pragma unroll
        for (int i = 0; i < 4; i++)
#pragma unroll
            for (int j = 0; j < 4; j++) {
                acc[i][j] = __builtin_amdgcn_mfma_f32_16x16x32_bf16(afl[i], bfh[j], acc[i][j], 0, 0, 0);
                acc[i][j] = __builtin_amdgcn_mfma_f32_16x16x32_bf16(afh[i], bfl[j], acc[i][j], 0, 0, 0);
                acc[i][j] = __builtin_amdgcn_mfma_f32_16x16x32_bf16(afh[i], bfh[j], acc[i][j], 0, 0, 0);
            }
    }
    float bc[4];
#pragma unroll
    for (int j = 0; j < 4; j++) bc[j] = bias[n0 + wn * 64 + j * 16 + (lane & 15)];
#pragma unroll
    for (int i = 0; i < 4; i++) {
#pragma unroll
        for (int j = 0; j < 4; j++) {
#pragma unroll
            for (int r = 0; r < 4; r++) {
                int rw = m0 + wm * 64 + i * 16 + (lane >> 4) * 4 + r;
                int cl = n0 + wn * 64 + j * 16 + (lane & 15);
                float v = acc[i][j][r] + bc[j];
                v = v >= 0.f ? v : 0.2f * v;
                if (OUTSPLIT) {
                    unsigned short hi = f2bf(v);
                    oh[(size_t)rw * N + cl] = hi;
                    ol[(size_t)rw * N + cl] = f2bf(v - bf2f(hi));
                } else {
                    of[(size_t)rw * N + cl] = v;
                }
            }
        }
    }
}

extern "C" void kernel_launch(void* const* d_in, const int* in_sizes, int n_in,
                              void* d_out, int out_size, void* d_ws, size_t ws_size,
                              hipStream_t stream)
{
    const float* x    = (const float*)d_in[0];
    const float* c1   = (const float*)d_in[1];
    const float* c2   = (const float*)d_in[2];
    const float* peW1 = (const float*)d_in[3];
    const float* peb1 = (const float*)d_in[4];
    const float* peW2 = (const float*)d_in[5];
    const float* peb2 = (const float*)d_in[6];
    const float* Wq   = (const float*)d_in[7];
    const float* Wk   = (const float*)d_in[8];
    const float* Wv   = (const float*)d_in[9];
    const float* lsc  = (const float*)d_in[10];
    const float* Wo   = (const float*)d_in[11];
    const float* bo   = (const float*)d_in[12];
    const float* g1   = (const float*)d_in[13];
    const float* be1  = (const float*)d_in[14];
    const float* g2   = (const float*)d_in[15];
    const float* be2  = (const float*)d_in[16];
    const float* g3   = (const float*)d_in[17];
    const float* be3  = (const float*)d_in[18];
    const float* mW1  = (const float*)d_in[19];
    const float* mb1  = (const float*)d_in[20];
    const float* mW2  = (const float*)d_in[21];
    const float* mb2  = (const float*)d_in[22];
    const float* muW1 = (const float*)d_in[23];
    const float* mub1 = (const float*)d_in[24];
    const float* muW2 = (const float*)d_in[25];
    const float* mub2 = (const float*)d_in[26];

    const size_t MB = (size_t)1 << 20;
    char* ws = (char*)d_ws;
    // Timeline-safe layout, 80.5 MiB total (unchanged from round 5)
    u64*            cand   = (u64*)(ws);
    float*          hbuf   = (float*)(ws);
    unsigned short* y1h    = (unsigned short*)(ws);
    unsigned short* y1l    = (unsigned short*)(ws + 16 * MB);
    unsigned short* hnh    = (unsigned short*)(ws + 32 * MB);
    unsigned short* hnl    = (unsigned short*)(ws + 48 * MB);
    u64*            c2c    = (u64*)(ws + 64 * MB);
    unsigned short* w1th   = (unsigned short*)(ws + 72 * MB);
    unsigned short* w1tl   = (unsigned short*)(ws + 74 * MB);
    unsigned short* w2th   = (unsigned short*)(ws + 76 * MB);
    unsigned short* w2tl   = (unsigned short*)(ws + 78 * MB);
    int*            knn    = (int*)(ws + 80 * MB);
    (void)in_sizes; (void)n_in; (void)out_size; (void)ws_size;

    wconv<<<dim3(16, 16, 2), 256, 0, stream>>>(muW1, muW2, w1th, w1tl, w2th, w2tl);
    topk_partial<<<dim3(TT / 256, NC, B_), 256, 0, stream>>>(c1, c2, cand);
    topk_merge1<<<dim3(TT / 64, 8, B_), 64, 0, stream>>>(cand, c2c);
    topk_merge2<<<dim3(TT / 64, B_), 64, 0, stream>>>(c2c, knn);
    tok_pe_m<<<dim3(512), 256, 0, stream>>>(x, c1, c2, knn, peW1, peb1, peW2, peb2, g1, be1, hbuf);
    tok_pe_v<<<dim3(512), 256, 0, stream>>>(x, c1, c2, knn, peW1, peb1, peW2, peb2, g1, be1, hbuf);
    tok_attn<<<dim3(512), 256, 0, stream>>>(x, knn, Wq, Wk, Wv, lsc, Wo, bo, g2, be2, hbuf);
    tok_mnh_m<<<dim3(512), 256, 0, stream>>>(hbuf, mW1, mb1, mW2, mb2, g3, be3, hnh, hnl);
    tok_mnh_v<<<dim3(512), 256, 0, stream>>>(hbuf, mW1, mb1, mW2, mb2, g3, be3, hnh, hnl);
    gemm_split<1><<<dim3(8, 64), 256, 0, stream>>>(hnh, hnl, w1th, w1tl, mub1,
                                                   y1h, y1l, (float*)nullptr, 8192, 1024, 1024);
    gemm_split<0><<<dim3(8, 64), 256, 0, stream>>>(y1h, y1l, w2th, w2tl, mub2,
                                                   (unsigned short*)nullptr, (unsigned short*)nullptr,
                                                   (float*)d_out, 8192, 1024, 1024);
}

// Round 12
// 701.084 us; speedup vs baseline: 1.2785x; 1.2785x over previous
//
#include <hip/hip_runtime.h>
#include <hip/hip_bf16.h>

#define B_    2
#define SSRC  8192
#define TT    4096
#define NHN   16
#define NC    64
#define CS    128           // SSRC / NC
#define LOG100D 4.605170185988091368035982909368

typedef short s16x8 __attribute__((ext_vector_type(8)));
typedef float f32x4 __attribute__((ext_vector_type(4)));
typedef double f64x4 __attribute__((ext_vector_type(4)));
typedef unsigned long long u64;

typedef const __attribute__((address_space(1))) void* gas_ptr;
typedef __attribute__((address_space(3))) void* las_ptr;
#define GLDS16(g, l) __builtin_amdgcn_global_load_lds((gas_ptr)(g), (las_ptr)(l), 16, 0, 0)

// wave-local LDS fence: scratch is per-wave, no cross-wave barrier needed
#define WFENCE asm volatile("s_waitcnt lgkmcnt(0)" ::: "memory")

__device__ __forceinline__ unsigned short f2bf(float f) {
    unsigned u = __float_as_uint(f);
    u = u + 0x7fffu + ((u >> 16) & 1u);
    return (unsigned short)(u >> 16);
}
__device__ __forceinline__ float bf2f(unsigned short h) {
    return __uint_as_float(((unsigned)h) << 16);
}
__device__ __forceinline__ double lrelu_d(double v) { return v >= 0.0 ? v : 0.2 * v; }
__device__ __forceinline__ double gelu_d(double u) {
    double a = 0.7978845608028654 * (u + 0.044715 * u * u * u);
    return 0.5 * u * (1.0 + tanh(a));
}
__device__ __forceinline__ double rsum16d(double v) {
    v += __shfl_xor(v, 1); v += __shfl_xor(v, 2);
    v += __shfl_xor(v, 4); v += __shfl_xor(v, 8);
    return v;
}
__device__ __forceinline__ double rmax16d(double v) {
    v = fmax(v, __shfl_xor(v, 1)); v = fmax(v, __shfl_xor(v, 2));
    v = fmax(v, __shfl_xor(v, 4)); v = fmax(v, __shfl_xor(v, 8));
    return v;
}
__device__ __forceinline__ double rsum64d(double v) {
    v += __shfl_xor(v, 1); v += __shfl_xor(v, 2); v += __shfl_xor(v, 4);
    v += __shfl_xor(v, 8); v += __shfl_xor(v, 16); v += __shfl_xor(v, 32);
    return v;
}

// ---- f64 MFMA layout discovery: returns candidate 0..7 or -1 ----
// candidate c = (dm<<2)|(am<<1)|bm with
//   am: A lane map  0: l=i+16k   1: l=4i+k      (A is 16x4: X[i][k])
//   bm: B lane map  0: l=j+16k   1: l=4j+k      (B is 4x16: W[k][j])
//   dm: D placement 0: i=4*lg+r  1: i=lg+4r     (col j = l&15 in both)
__device__ __forceinline__ int mfma64_discover() {
    int lane = threadIdx.x & 63;
    int l15 = lane & 15, lg = lane >> 4;
    double va = (double)(1 + ((lane * 37) % 61));
    double vb = (double)(2 + ((lane * 53) % 59));
    f64x4 d = (f64x4){0.0, 0.0, 0.0, 0.0};
    d = __builtin_amdgcn_mfma_f64_16x16x4f64(va, vb, d, 0, 0, 0);
    int found = -1;
#pragma unroll
    for (int c = 0; c < 8; c++) {
        int dm = (c >> 2) & 1, am = (c >> 1) & 1, bm = c & 1;
        bool ok = true;
#pragma unroll
        for (int r = 0; r < 4; r++) {
            int i = dm ? (lg + 4 * r) : (4 * lg + r);
            int j = l15;
            double e = 0.0;
#pragma unroll
            for (int k = 0; k < 4; k++) {
                int la = am ? (4 * i + k) : (i + 16 * k);
                int lb = bm ? (4 * j + k) : (j + 16 * k);
                e += (double)(1 + ((la * 37) % 61)) * (double)(2 + ((lb * 53) % 59));
            }
            ok = ok && (d[r] == e);
        }
        if (__all(ok) && found < 0) found = c;
    }
    return found;   // wave-uniform, deterministic
}

// ---- branch-free 16-element sorting primitives (u64 keys, static reg indices) ----
__device__ __forceinline__ void ce(u64 &a, u64 &b) {
    bool c = a < b; u64 lo = c ? a : b; u64 hi = c ? b : a; a = lo; b = hi;
}
// Batcher merge-exchange sort, 63 CEs, ascending
__device__ __forceinline__ void sort16(u64 (&k)[16]) {
    ce(k[0],k[8]); ce(k[1],k[9]); ce(k[2],k[10]); ce(k[3],k[11]);
    ce(k[4],k[12]); ce(k[5],k[13]); ce(k[6],k[14]); ce(k[7],k[15]);
    ce(k[0],k[4]); ce(k[1],k[5]); ce(k[2],k[6]); ce(k[3],k[7]);
    ce(k[8],k[12]); ce(k[9],k[13]); ce(k[10],k[14]); ce(k[11],k[15]);
    ce(k[4],k[8]); ce(k[5],k[9]); ce(k[6],k[10]); ce(k[7],k[11]);
    ce(k[0],k[2]); ce(k[1],k[3]); ce(k[4],k[6]); ce(k[5],k[7]);
    ce(k[8],k[10]); ce(k[9],k[11]); ce(k[12],k[14]); ce(k[13],k[15]);
    ce(k[2],k[8]); ce(k[3],k[9]); ce(k[6],k[12]); ce(k[7],k[13]);
    ce(k[2],k[4]); ce(k[3],k[5]); ce(k[6],k[8]); ce(k[7],k[9]);
    ce(k[10],k[12]); ce(k[11],k[13]);
    ce(k[0],k[1]); ce(k[2],k[3]); ce(k[4],k[5]); ce(k[6],k[7]);
    ce(k[8],k[9]); ce(k[10],k[11]); ce(k[12],k[13]); ce(k[14],k[15]);
    ce(k[1],k[8]); ce(k[3],k[10]); ce(k[5],k[12]); ce(k[7],k[14]);
    ce(k[1],k[4]); ce(k[3],k[6]); ce(k[5],k[8]); ce(k[7],k[10]);
    ce(k[9],k[12]); ce(k[11],k[14]);
    ce(k[1],k[2]); ce(k[3],k[4]); ce(k[5],k[6]); ce(k[7],k[8]);
    ce(k[9],k[10]); ce(k[11],k[12]); ce(k[13],k[14]);
}
// bitonic merge of a unimodal 16-seq -> sorted asc, 32 CEs
__device__ __forceinline__ void bmerge16(u64 (&k)[16]) {
    ce(k[0],k[8]); ce(k[1],k[9]); ce(k[2],k[10]); ce(k[3],k[11]);
    ce(k[4],k[12]); ce(k[5],k[13]); ce(k[6],k[14]); ce(k[7],k[15]);
    ce(k[0],k[4]); ce(k[1],k[5]); ce(k[2],k[6]); ce(k[3],k[7]);
    ce(k[8],k[12]); ce(k[9],k[13]); ce(k[10],k[14]); ce(k[11],k[15]);
    ce(k[0],k[2]); ce(k[1],k[3]); ce(k[4],k[6]); ce(k[5],k[7]);
    ce(k[8],k[10]); ce(k[9],k[11]); ce(k[12],k[14]); ce(k[13],k[15]);
    ce(k[0],k[1]); ce(k[2],k[3]); ce(k[4],k[5]); ce(k[6],k[7]);
    ce(k[8],k[9]); ce(k[10],k[11]); ce(k[12],k[13]); ce(k[14],k[15]);
}
// keep 16 smallest of sorted L and sorted B (both asc); L out sorted asc
__device__ __forceinline__ void merge_keep16(u64 (&L)[16], const u64 (&B)[16]) {
#pragma unroll
    for (int i = 0; i < 16; i++) { u64 bb = B[15 - i]; L[i] = L[i] < bb ? L[i] : bb; }
    bmerge16(L);
}

// ---------------- top-k phase A: per-chunk sorted top-16 (batch-bitonic) ----------------
__global__ __launch_bounds__(256) void topk_partial(
    const float* __restrict__ c1, const float* __restrict__ c2,
    u64* __restrict__ cand)
{
    int t = blockIdx.x * 256 + threadIdx.x;
    int ch = blockIdx.y, b = blockIdx.z;
    const float* p1 = c1 + ((size_t)b * SSRC + (size_t)ch * CS) * TT + t;
    const float* p2 = c2 + ((size_t)b * SSRC + (size_t)ch * CS) * TT + t;
    u64 k[16];
#pragma unroll
    for (int j = 0; j < 16; j++) k[j] = ~0ull;
    int sbase = ch * CS;
    for (int s = 0; s < CS; s += 16) {
        u64 bt[16];
#pragma unroll
        for (int u = 0; u < 16; u++) {
            float a_ = p1[(size_t)(s + u) * TT];
            float b_ = p2[(size_t)(s + u) * TT];
            // exact IEEE mul/add to match numpy f32 (no fma contraction)
            float dd = __fadd_rn(__fmul_rn(a_, a_), __fmul_rn(b_, b_));
            bt[u] = ((u64)__float_as_uint(dd) << 32) | (unsigned)(sbase + s + u);
        }
        sort16(bt);
        merge_keep16(k, bt);
    }
    u64* dst = cand + ((size_t)(b * NC + ch) * 16) * TT + t;
#pragma unroll
    for (int j = 0; j < 16; j++) dst[(size_t)j * TT] = k[j];
}

// ---------------- top-k merge level 1: 64 chunk-lists -> 8 group-lists ----------------
__global__ __launch_bounds__(64) void topk_merge1(
    const u64* __restrict__ cand, u64* __restrict__ c2c)
{
    int t = blockIdx.x * 64 + threadIdx.x;
    int g = blockIdx.y, b = blockIdx.z;
    u64 k[16];
#pragma unroll
    for (int j = 0; j < 16; j++) k[j] = ~0ull;
    for (int c = g * 8; c < g * 8 + 8; c++) {
        const u64* src = cand + ((size_t)(b * NC + c) * 16) * TT + t;
        u64 bt[16];
#pragma unroll
        for (int j = 0; j < 16; j++) bt[j] = src[(size_t)j * TT];
        merge_keep16(k, bt);
    }
    u64* dst = c2c + ((size_t)((b * 8 + g) * 16)) * TT + t;
#pragma unroll
    for (int j = 0; j < 16; j++) dst[(size_t)j * TT] = k[j];
}

// ---------------- top-k merge level 2: 8 lists -> sorted knn indices ----------------
__global__ __launch_bounds__(64) void topk_merge2(
    const u64* __restrict__ c2c, int* __restrict__ knn)
{
    int t = blockIdx.x * 64 + threadIdx.x;
    int b = blockIdx.y;
    u64 k[16];
#pragma unroll
    for (int j = 0; j < 16; j++) k[j] = ~0ull;
    for (int c = 0; c < 8; c++) {
        const u64* src = c2c + ((size_t)(b * 8 + c) * 16) * TT + t;
        u64 bt[16];
#pragma unroll
        for (int j = 0; j < 16; j++) bt[j] = src[(size_t)j * TT];
        merge_keep16(k, bt);
    }
#pragma unroll
    for (int j = 0; j < 16; j++)
        knn[((size_t)b * TT + t) * 16 + j] = (int)(unsigned)(k[j] & 0xffffffffull);
}

// ------- weight transpose + split-bf16 convert (mu_W1/mu_W2 -> W^T hi/lo) -------
__global__ __launch_bounds__(256) void wconv(
    const float* __restrict__ Wa, const float* __restrict__ Wb,
    unsigned short* __restrict__ Oah, unsigned short* __restrict__ Oal,
    unsigned short* __restrict__ Obh, unsigned short* __restrict__ Obl)
{
    const float* W = blockIdx.z ? Wb : Wa;
    unsigned short* Oh = blockIdx.z ? Obh : Oah;
    unsigned short* Ol = blockIdx.z ? Obl : Oal;
    __shared__ float tile[64][65];
    int tx = threadIdx.x & 63, ty = threadIdx.x >> 6;
    int n0 = blockIdx.x * 64, k0 = blockIdx.y * 64;
#pragma unroll
    for (int r = ty; r < 64; r += 4) tile[r][tx] = W[(size_t)(k0 + r) * 1024 + n0 + tx];
    __syncthreads();
#pragma unroll
    for (int r = ty; r < 64; r += 4) {
        float v = tile[tx][r];
        unsigned short hi = f2bf(v);
        Oh[(size_t)(n0 + r) * 1024 + k0 + tx] = hi;
        Ol[(size_t)(n0 + r) * 1024 + k0 + tx] = f2bf(v - bf2f(hi));
    }
}

// ============ stage A (MFMA variant, r10 form): gather + PE MLP + LN1 -> h ============
// peW2 staged in LDS, row stride 66 (bank-conflict-free)
__global__ __launch_bounds__(256) void tok_pe_m(
    const float* __restrict__ x, const float* __restrict__ c1, const float* __restrict__ c2,
    const int* __restrict__ knn,
    const float* __restrict__ peW1, const float* __restrict__ peb1,
    const float* __restrict__ peW2, const float* __restrict__ peb2,
    const float* __restrict__ g1, const float* __restrict__ be1,
    float* __restrict__ hout)
{
    int cand = mfma64_discover();
    if (cand < 0) return;   // block-uniform
    __shared__ float s_peW1[256], s_peb1[128], s_peW2[8448], s_peb2[64], s_g1[64], s_be1[64];
    __shared__ float s_scr[4][2352];
    int tid = threadIdx.x, lane = tid & 63, w = tid >> 6;
    if (tid < 256) s_peW1[tid] = peW1[tid];
    if (tid < 128) s_peb1[tid] = peb1[tid];
    if (tid < 64) { s_peb2[tid] = peb2[tid]; s_g1[tid] = g1[tid]; s_be1[tid] = be1[tid]; }
    for (int i = tid; i < 8192; i += 256) s_peW2[(i >> 6) * 66 + (i & 63)] = peW2[i];
    __syncthreads();

    int l15 = lane & 15, lg = lane >> 4;
    int am = (cand >> 1) & 1, bm = cand & 1, dm = (cand >> 2) & 1;
    int a_i = am ? (lane >> 2) : l15;
    int a_k = am ? (lane & 3)  : lg;
    int b_k = bm ? (lane & 3)  : lg;
    int b_j = bm ? (lane >> 2) : l15;
    int i0 = dm ? lg : 4 * lg;
    int istep = dm ? 4 : 1;

    float* big = s_scr[w];
    float* sc1 = big + 2304; float* sc2 = big + 2320; float* sx = big + 2336;
    double w0a = s_peW1[lane], w1a = s_peW1[128 + lane], ba = s_peb1[lane];
    double w0b = s_peW1[64 + lane], w1b = s_peW1[192 + lane], bbv = s_peb1[64 + lane];
    double g1v[4], be1v[4], pb2v[4];
#pragma unroll
    for (int j = 0; j < 4; j++) {
        g1v[j]  = (double)s_g1[j * 16 + l15];
        be1v[j] = (double)s_be1[j * 16 + l15];
        pb2v[j] = (double)s_peb2[j * 16 + l15];
    }

    for (int it = 0; it < 4; ++it) {
        int tk = blockIdx.x * 16 + w * 4 + it;
        int bb = tk >> 12, tt = tk & (TT - 1);
        if (lane < 16) {
            int s = knn[(size_t)tk * 16 + lane];
            sc1[lane] = c1[((size_t)bb * SSRC + s) * TT + tt];
            sc2[lane] = c2[((size_t)bb * SSRC + s) * TT + tt];
            sx[lane]  = x[bb * SSRC + s];
        }
        WFENCE;
#pragma unroll
        for (int n = 0; n < 16; n++) {
            double a_ = (double)sc1[n], b_ = (double)sc2[n];
            big[lane * 18 + n]        = (float)gelu_d(a_ * w0a + b_ * w1a + ba);
            big[(lane + 64) * 18 + n] = (float)gelu_d(a_ * w0b + b_ * w1b + bbv);
        }
        WFENCE;
        // PE2 via f64 MFMA (discovered layout): OUT[n][e] = gT^T @ W2
        f64x4 acc[4];
#pragma unroll
        for (int j = 0; j < 4; j++) acc[j] = (f64x4){0.0, 0.0, 0.0, 0.0};
        for (int ks = 0; ks < 32; ks++) {
            double a = (double)big[(4 * ks + a_k) * 18 + a_i];
            const float* wrow = &s_peW2[(4 * ks + b_k) * 66 + b_j];
#pragma unroll
            for (int j = 0; j < 4; j++)
                acc[j] = __builtin_amdgcn_mfma_f64_16x16x4f64(a, (double)wrow[j * 16], acc[j], 0, 0, 0);
        }
        float* op = hout + (size_t)tk * 1024;
#pragma unroll
        for (int r = 0; r < 4; r++) {
            int n = i0 + istep * r;
            double xr = (double)sx[n];
            double v[4], s = 0.0;
#pragma unroll
            for (int j = 0; j < 4; j++) { v[j] = acc[j][r] + pb2v[j] + xr; s += v[j]; }
            double m = rsum16d(s) * (1.0 / 64.0);
            double q = 0.0;
#pragma unroll
            for (int j = 0; j < 4; j++) { double d = v[j] - m; q += d * d; }
            double var = rsum16d(q) * (1.0 / 64.0);
            double rs = sqrt(var + 1e-5);
#pragma unroll
            for (int j = 0; j < 4; j++)
                op[n * 64 + j * 16 + l15] = (float)((v[j] - m) / rs * g1v[j] + be1v[j]);
        }
    }
}

// ============ stage A (VALU fallback, round-7 numerics; LDS stride-66 weights) ============
__global__ __launch_bounds__(256) void tok_pe_v(
    const float* __restrict__ x, const float* __restrict__ c1, const float* __restrict__ c2,
    const int* __restrict__ knn,
    const float* __restrict__ peW1, const float* __restrict__ peb1,
    const float* __restrict__ peW2, const float* __restrict__ peb2,
    const float* __restrict__ g1, const float* __restrict__ be1,
    float* __restrict__ hout)
{
    int cand = mfma64_discover();
    if (cand >= 0) return;
    __shared__ float s_peW1[256], s_peb1[128], s_peW2[8448], s_peb2[64], s_g1[64], s_be1[64];
    __shared__ float s_scr[4][2352];
    int tid = threadIdx.x, lane = tid & 63, w = tid >> 6;
    if (tid < 256) s_peW1[tid] = peW1[tid];
    if (tid < 128) s_peb1[tid] = peb1[tid];
    if (tid < 64) { s_peb2[tid] = peb2[tid]; s_g1[tid] = g1[tid]; s_be1[tid] = be1[tid]; }
    for (int i = tid; i < 8192; i += 256) s_peW2[(i >> 6) * 66 + (i & 63)] = peW2[i];
    __syncthreads();

    float* big = s_scr[w];
    float* sc1 = big + 2304; float* sc2 = big + 2320; float* sx = big + 2336;
    double w0a = s_peW1[lane], w1a = s_peW1[128 + lane], ba = s_peb1[lane];
    double w0b = s_peW1[64 + lane], w1b = s_peW1[192 + lane], bbv = s_peb1[64 + lane];
    double gv = (double)s_g1[lane], bv = (double)s_be1[lane];
    double pb2 = (double)s_peb2[lane];

    for (int it = 0; it < 4; ++it) {
        int tk = blockIdx.x * 16 + w * 4 + it;
        int bb = tk >> 12, tt = tk & (TT - 1);
        if (lane < 16) {
            int s = knn[(size_t)tk * 16 + lane];
            sc1[lane] = c1[((size_t)bb * SSRC + s) * TT + tt];
            sc2[lane] = c2[((size_t)bb * SSRC + s) * TT + tt];
            sx[lane]  = x[bb * SSRC + s];
        }
        WFENCE;
#pragma unroll
        for (int n = 0; n < 16; n++) {
            double a_ = (double)sc1[n], b_ = (double)sc2[n];
            big[lane * 18 + n]        = (float)gelu_d(a_ * w0a + b_ * w1a + ba);
            big[(lane + 64) * 18 + n] = (float)gelu_d(a_ * w0b + b_ * w1b + bbv);
        }
        WFENCE;
        double acc[16];
#pragma unroll
        for (int n = 0; n < 16; n++) acc[n] = pb2;
        for (int f = 0; f < 128; f++) {
            double wv = (double)s_peW2[f * 66 + lane];
#pragma unroll
            for (int n = 0; n < 16; n += 2) {
                float2 gvv = *(const float2*)&big[f * 18 + n];
                acc[n]     += (double)gvv.x * wv;
                acc[n + 1] += (double)gvv.y * wv;
            }
        }
        float* op = hout + (size_t)tk * 1024 + lane;
#pragma unroll
        for (int n = 0; n < 16; n++) {
            double v = acc[n] + (double)sx[n];
            double m = rsum64d(v) * (1.0 / 64.0);
            double d = v - m;
            double var = rsum64d(d * d) * (1.0 / 64.0);
            op[n * 64] = (float)(d / sqrt(var + 1e-5) * gv + bv);
        }
    }
}

// ============ stage B: q/k VALU (LDS-staged stride-66 Wq/Wk) + cosine attn + WoV + LN2 ============
__global__ __launch_bounds__(256) void tok_attn(
    const float* __restrict__ x, const int* __restrict__ knn,
    const float* __restrict__ Wq, const float* __restrict__ Wk,
    const float* __restrict__ Wv, const float* __restrict__ lsc,
    const float* __restrict__ Wo, const float* __restrict__ bo,
    const float* __restrict__ g2, const float* __restrict__ be2,
    float* __restrict__ hio)
{
    __shared__ float s_Wq[4224], s_Wk[4224], s_WoV[256], s_bo[64], s_g2[64], s_be2[64];
    __shared__ float s_scr[4][2320];
    int tid = threadIdx.x, lane = tid & 63, w = tid >> 6;
    if (tid < 64) {
        s_bo[tid] = bo[tid]; s_g2[tid] = g2[tid]; s_be2[tid] = be2[tid];
        for (int hh = 0; hh < 4; hh++) {
            double a = 0.0;
            for (int hd = 0; hd < 16; hd++)
                a += (double)Wv[hh * 16 + hd] * (double)Wo[(hh * 16 + hd) * 64 + tid];
            s_WoV[hh * 64 + tid] = (float)a;
        }
    }
    for (int i = tid; i < 4096; i += 256) {
        s_Wq[(i >> 6) * 66 + (i & 63)] = Wq[i];
        s_Wk[(i >> 6) * 66 + (i & 63)] = Wk[i];
    }
    __syncthreads();

    int head = lane >> 4, mm = lane & 15;
    double scaleh = exp(fmin((double)lsc[head], LOG100D));
    double wov0 = (double)s_WoV[lane], wov1 = (double)s_WoV[64 + lane];
    double wov2 = (double)s_WoV[128 + lane], wov3 = (double)s_WoV[192 + lane];
    double gv = (double)s_g2[lane], bv = (double)s_be2[lane], bov = (double)s_bo[lane];
    float* big = s_scr[w];
    float* sx = big + 2304;

    for (int it = 0; it < 4; ++it) {
        int tk = blockIdx.x * 16 + w * 4 + it;
        int bb = tk >> 12;
        if (lane < 16) {
            int s = knn[(size_t)tk * 16 + lane];
            sx[lane] = x[bb * SSRC + s];
        }
        float* hp = hio + (size_t)tk * 1024 + lane;
        double h[16];
#pragma unroll
        for (int n = 0; n < 16; n++) {
            h[n] = (double)hp[n * 64];
            big[lane * 18 + n] = (float)h[n];   // hT[k=lane][n]
        }
        WFENCE;
        // q = h@Wq, k = h@Wk (f64, LDS-staged weights)
        double q[16], k2[16];
#pragma unroll
        for (int n = 0; n < 16; n++) { q[n] = 0.0; k2[n] = 0.0; }
        for (int kk = 0; kk < 64; kk++) {
            double wq = (double)s_Wq[kk * 66 + lane], wk = (double)s_Wk[kk * 66 + lane];
#pragma unroll
            for (int n = 0; n < 16; n += 2) {
                float2 hv = *(const float2*)&big[kk * 18 + n];
                q[n]  += (double)hv.x * wq; q[n + 1]  += (double)hv.y * wq;
                k2[n] += (double)hv.x * wk; k2[n + 1] += (double)hv.y * wk;
            }
        }
#pragma unroll
        for (int n = 0; n < 16; n++) {
            double sq = rsum16d(q[n] * q[n]);   q[n]  /= sqrt(sq + 1e-12);
            double sk = rsum16d(k2[n] * k2[n]); k2[n] /= sqrt(sk + 1e-12);
        }
        WFENCE;   // ensure hT reads retired before overwrite
#pragma unroll
        for (int n = 0; n < 16; n++) {
            big[lane * 18 + n]        = (float)q[n];
            big[1152 + lane * 18 + n] = (float)k2[n];
        }
        WFENCE;
        // S = qn@kn^T * scale, softmax, A = att @ x
        double A_[16];
        {
            double S[16];
#pragma unroll
            for (int n = 0; n < 16; n++) S[n] = 0.0;
            for (int hd = 0; hd < 16; hd++) {
                int r = head * 16 + hd;
                double kf = (double)big[1152 + r * 18 + mm];
#pragma unroll
                for (int n = 0; n < 16; n += 2) {
                    float2 qq = *(const float2*)&big[r * 18 + n];
                    S[n] += (double)qq.x * kf; S[n + 1] += (double)qq.y * kf;
                }
            }
            double xv = (double)sx[mm];
#pragma unroll
            for (int n = 0; n < 16; n++) {
                double sv = S[n] * scaleh;
                double mx = rmax16d(sv);
                double e = exp(sv - mx);
                double se = rsum16d(e);
                A_[n] = rsum16d((e / se) * xv);
            }
        }
#pragma unroll
        for (int n = 0; n < 16; n++) {
            double a0 = __shfl(A_[n], mm), a1 = __shfl(A_[n], 16 + mm);
            double a2 = __shfl(A_[n], 32 + mm), a3 = __shfl(A_[n], 48 + mm);
            double v = h[n] + a0 * wov0 + a1 * wov1 + a2 * wov2 + a3 * wov3 + bov;
            double m = rsum64d(v) * (1.0 / 64.0);
            double d = v - m;
            double var = rsum64d(d * d) * (1.0 / 64.0);
            hp[n * 64] = (float)(d / sqrt(var + 1e-5) * gv + bv);
        }
    }
}

// ============ stage C (MFMA variant, r10 form): mnh MLP + LN3 -> hn split-bf16 ============
// mW1 staged in LDS, row stride 130
__global__ __launch_bounds__(256) void tok_mnh_m(
    const float* __restrict__ hin,
    const float* __restrict__ mW1, const float* __restrict__ mb1,
    const float* __restrict__ mW2, const float* __restrict__ mb2,
    const float* __restrict__ g3, const float* __restrict__ be3,
    unsigned short* __restrict__ hnh, unsigned short* __restrict__ hnl)
{
    int cand = mfma64_discover();
    if (cand < 0) return;
    __shared__ float s_mW1[8320], s_mb1[128], s_mW2[128], s_g3[1024], s_be3[1024];
    __shared__ float s_scr[4][1152];
    int tid = threadIdx.x, lane = tid & 63, w = tid >> 6;
    if (tid < 128) { s_mb1[tid] = mb1[tid]; s_mW2[tid] = mW2[tid]; }
    for (int i = tid; i < 8192; i += 256) s_mW1[(i >> 7) * 130 + (i & 127)] = mW1[i];
    for (int i = tid; i < 1024; i += 256) { s_g3[i] = g3[i]; s_be3[i] = be3[i]; }
    __syncthreads();

    int l15 = lane & 15, lg = lane >> 4;
    int am = (cand >> 1) & 1, bm = cand & 1, dm = (cand >> 2) & 1;
    int a_i = am ? (lane >> 2) : l15;
    int a_k = am ? (lane & 3)  : lg;
    int b_k = bm ? (lane & 3)  : lg;
    int b_j = bm ? (lane >> 2) : l15;

    double mb2s = (double)mb2[0];
    double mb1v[8], w2v[8];
#pragma unroll
    for (int j = 0; j < 8; j++) {
        mb1v[j] = (double)s_mb1[j * 16 + l15];
        w2v[j]  = (double)s_mW2[j * 16 + l15];
    }
    float* big = s_scr[w];

    for (int it = 0; it < 4; ++it) {
        int tk = blockIdx.x * 16 + w * 4 + it;
        const float* hp = hin + (size_t)tk * 1024 + lane;
        double h[16];
#pragma unroll
        for (int n = 0; n < 16; n++) {
            h[n] = (double)hp[n * 64];
            big[lane * 18 + n] = (float)h[n];
        }
        WFENCE;
        f64x4 acc[8];
#pragma unroll
        for (int j = 0; j < 8; j++) acc[j] = (f64x4){0.0, 0.0, 0.0, 0.0};
        for (int ks = 0; ks < 16; ks++) {
            double a = (double)big[(4 * ks + a_k) * 18 + a_i];
            const float* wrow = &s_mW1[(4 * ks + b_k) * 130 + b_j];
#pragma unroll
            for (int j = 0; j < 8; j++)
                acc[j] = __builtin_amdgcn_mfma_f64_16x16x4f64(a, (double)wrow[j * 16], acc[j], 0, 0, 0);
        }
        double p[4];
#pragma unroll
        for (int r = 0; r < 4; r++) {
            double s = 0.0;
#pragma unroll
            for (int j = 0; j < 8; j++) {
                double t = acc[j][r] + mb1v[j];
                s += lrelu_d(t) * w2v[j];
            }
            p[r] = rsum16d(s);
        }
        // broadcast p (lane group owning row n -> all lanes)
        if (dm == 0) {
#pragma unroll
            for (int n = 0; n < 16; n++) {
                double pn = __shfl(p[n & 3], (n >> 2) * 16);
                h[n] += lrelu_d(pn + mb2s);
            }
        } else {
#pragma unroll
            for (int n = 0; n < 16; n++) {
                double pn = __shfl(p[n >> 2], (n & 3) * 16);
                h[n] += lrelu_d(pn + mb2s);
            }
        }
        double s1 = 0.0;
#pragma unroll
        for (int n = 0; n < 16; n++) s1 += h[n];
        s1 = rsum64d(s1) * (1.0 / 1024.0);
        double s2v = 0.0;
#pragma unroll
        for (int n = 0; n < 16; n++) { double d = h[n] - s1; s2v += d * d; }
        s2v = rsum64d(s2v) * (1.0 / 1024.0);
        double rs = 1.0 / sqrt(s2v + 1e-5);
        unsigned short* oph = hnh + (size_t)tk * 1024 + lane;
        unsigned short* opl = hnl + (size_t)tk * 1024 + lane;
#pragma unroll
        for (int n = 0; n < 16; n++) {
            double v = (h[n] - s1) * rs * (double)s_g3[n * 64 + lane] + (double)s_be3[n * 64 + lane];
            unsigned short hi = f2bf((float)v);
            oph[n * 64] = hi;
            opl[n * 64] = f2bf((float)(v - (double)bf2f(hi)));
        }
    }
}

// ============ stage C (VALU fallback, round-7 numerics; LDS stride-130 mW1) ============
__global__ __launch_bounds__(256) void tok_mnh_v(
    const float* __restrict__ hin,
    const float* __restrict__ mW1, const float* __restrict__ mb1,
    const float* __restrict__ mW2, const float* __restrict__ mb2,
    const float* __restrict__ g3, const float* __restrict__ be3,
    unsigned short* __restrict__ hnh, unsigned short* __restrict__ hnl)
{
    int cand = mfma64_discover();
    if (cand >= 0) return;
    __shared__ float s_mW1[8320], s_mb1[128], s_mW2[128], s_g3[1024], s_be3[1024];
    __shared__ float s_scr[4][1152];
    int tid = threadIdx.x, lane = tid & 63, w = tid >> 6;
    if (tid < 128) { s_mb1[tid] = mb1[tid]; s_mW2[tid] = mW2[tid]; }
    for (int i = tid; i < 8192; i += 256) s_mW1[(i >> 7) * 130 + (i & 127)] = mW1[i];
    for (int i = tid; i < 1024; i += 256) { s_g3[i] = g3[i]; s_be3[i] = be3[i]; }
    __syncthreads();

    double mb2s = (double)mb2[0];
    double mb1a = (double)s_mb1[lane], mb1b = (double)s_mb1[64 + lane];
    double w2a = (double)s_mW2[lane], w2b = (double)s_mW2[64 + lane];
    float* big = s_scr[w];

    for (int it = 0; it < 4; ++it) {
        int tk = blockIdx.x * 16 + w * 4 + it;
        const float* hp = hin + (size_t)tk * 1024 + lane;
        double h[16];
#pragma unroll
        for (int n = 0; n < 16; n++) {
            h[n] = (double)hp[n * 64];
            big[lane * 18 + n] = (float)h[n];
        }
        WFENCE;
        double t1a[16], t1b[16];
#pragma unroll
        for (int n = 0; n < 16; n++) { t1a[n] = mb1a; t1b[n] = mb1b; }
        for (int kk = 0; kk < 64; kk++) {
            double wa = (double)s_mW1[kk * 130 + lane], wb = (double)s_mW1[kk * 130 + 64 + lane];
#pragma unroll
            for (int n = 0; n < 16; n += 2) {
                float2 hv = *(const float2*)&big[kk * 18 + n];
                t1a[n] += (double)hv.x * wa; t1a[n + 1] += (double)hv.y * wa;
                t1b[n] += (double)hv.x * wb; t1b[n + 1] += (double)hv.y * wb;
            }
        }
#pragma unroll
        for (int n = 0; n < 16; n++) {
            double p = lrelu_d(t1a[n]) * w2a + lrelu_d(t1b[n]) * w2b;
            p = rsum64d(p);
            h[n] += lrelu_d(p + mb2s);
        }
        double s1 = 0.0;
#pragma unroll
        for (int n = 0; n < 16; n++) s1 += h[n];
        s1 = rsum64d(s1) * (1.0 / 1024.0);
        double s2v = 0.0;
#pragma unroll
        for (int n = 0; n < 16; n++) { double d = h[n] - s1; s2v += d * d; }
        s2v = rsum64d(s2v) * (1.0 / 1024.0);
        double rs = 1.0 / sqrt(s2v + 1e-5);
        unsigned short* oph = hnh + (size_t)tk * 1024 + lane;
        unsigned short* opl = hnl + (size_t)tk * 1024 + lane;
#pragma unroll
        for (int n = 0; n < 16; n++) {
            double v = (h[n] - s1) * rs * (double)s_g3[n * 64 + lane] + (double)s_be3[n * 64 + lane];
            unsigned short hi = f2bf((float)v);
            oph[n * 64] = hi;
            opl[n * 64] = f2bf((float)(v - (double)bf2f(hi)));
        }
    }
}

// ------- split-bf16 MFMA GEMM: out = lrelu(A@B + bias), A=Ah+Al, B=Bh+Bl -------
#define AH_OFF 0
#define AL_OFF 4096
#define BH_OFF 8192
#define BL_OFF 12288
template<int OUTSPLIT>
__global__ __launch_bounds__(256) void gemm_split(
    const unsigned short* __restrict__ Ah, const unsigned short* __restrict__ Al,
    const unsigned short* __restrict__ Bh, const unsigned short* __restrict__ Bl,
    const float* __restrict__ bias,
    unsigned short* __restrict__ oh, unsigned short* __restrict__ ol,
    float* __restrict__ of, int M, int N, int K)
{
    __shared__ unsigned short SM[16384];
    int tid = threadIdx.x, lane = tid & 63, w = tid >> 6;
    int wm = w >> 1, wn = w & 1;
    int m0 = blockIdx.y * 128, n0 = blockIdx.x * 128;
    f32x4 acc[4][4];
#pragma unroll
    for (int i = 0; i < 4; i++)
#pragma unroll
        for (int j = 0; j < 4; j++) acc[i][j] = (f32x4){0.f, 0.f, 0.f, 0.f};
    int row = tid >> 2, c8 = (tid & 3) * 8;
    size_t aoff = (size_t)(m0 + row) * K + c8;
    size_t boff = (size_t)(n0 + row) * K + c8;
    for (int kk = 0; kk < K; kk += 32) {
        __syncthreads();
        GLDS16(Ah + aoff + kk,                   SM + AH_OFF + tid * 8);
        GLDS16(Ah + aoff + (size_t)64 * K + kk,  SM + AH_OFF + 2048 + tid * 8);
        GLDS16(Al + aoff + kk,                   SM + AL_OFF + tid * 8);
        GLDS16(Al + aoff + (size_t)64 * K + kk,  SM + AL_OFF + 2048 + tid * 8);
        GLDS16(Bh + boff + kk,                   SM + BH_OFF + tid * 8);
        GLDS16(Bh + boff + (size_t)64 * K + kk,  SM + BH_OFF + 2048 + tid * 8);
        GLDS16(Bl + boff + kk,                   SM + BL_OFF + tid * 8);
        GLDS16(Bl + boff + (size_t)64 * K + kk,  SM + BL_OFF + 2048 + tid * 8);
        asm volatile("s_waitcnt vmcnt(0)" ::: "memory");
        __syncthreads();
        int kh = (lane >> 4) * 8, rA = wm * 64 + (lane & 15), rB = wn * 64 + (lane & 15);
        s16x8 afh[4], afl[4], bfh[4], bfl[4];
#pragma unroll
        for (int i = 0; i < 4; i++) {
            afh[i] = *(const s16x8*)&SM[AH_OFF + (rA + i * 16) * 32 + kh];
            afl[i] = *(const s16x8*)&SM[AL_OFF + (rA + i * 16) * 32 + kh];
            bfh[i] = *(const s16x8*)&SM[BH_OFF + (rB + i * 16) * 32 + kh];
            bfl[i] = *(const s16x8*)&SM[BL_OFF + (rB + i * 16) * 32 + kh];
        }
#pragma unroll
        for (int i = 0; i < 4; i++)
#pragma unroll
            for (int j = 0; j < 4; j++) {
                acc[i][j] = __builtin_amdgcn_mfma_f32_16x16x32_bf16(afl[i], bfh[j], acc[i][j], 0, 0, 0);
                acc[i][j] = __builtin_amdgcn_mfma_f32_16x16x32_bf16(afh[i], bfl[j], acc[i][j], 0, 0, 0);
                acc[i][j] = __builtin_amdgcn_mfma_f32_16x16x32_bf16(afh[i], bfh[j], acc[i][j], 0, 0, 0);
            }
    }
    float bc[4];
#pragma unroll
    for (int j = 0; j < 4; j++) bc[j] = bias[n0 + wn * 64 + j * 16 + (lane & 15)];
#pragma unroll
    for (int i = 0; i < 4; i++) {
#pragma unroll
        for (int j = 0; j < 4; j++) {
#pragma unroll
            for (int r = 0; r < 4; r++) {
                int rw = m0 + wm * 64 + i * 16 + (lane >> 4) * 4 + r;
                int cl = n0 + wn * 64 + j * 16 + (lane & 15);
                float v = acc[i][j][r] + bc[j];
                v = v >= 0.f ? v : 0.2f * v;
                if (OUTSPLIT) {
                    unsigned short hi = f2bf(v);
                    oh[(size_t)rw * N + cl] = hi;
                    ol[(size_t)rw * N + cl] = f2bf(v - bf2f(hi));
                } else {
                    of[(size_t)rw * N + cl] = v;
                }
            }
        }
    }
}

extern "C" void kernel_launch(void* const* d_in, const int* in_sizes, int n_in,
                              void* d_out, int out_size, void* d_ws, size_t ws_size,
                              hipStream_t stream)
{
    const float* x    = (const float*)d_in[0];
    const float* c1   = (const float*)d_in[1];
    const float* c2   = (const float*)d_in[2];
    const float* peW1 = (const float*)d_in[3];
    const float* peb1 = (const float*)d_in[4];
    const float* peW2 = (const float*)d_in[5];
    const float* peb2 = (const float*)d_in[6];
    const float* Wq   = (const float*)d_in[7];
    const float* Wk   = (const float*)d_in[8];
    const float* Wv   = (const float*)d_in[9];
    const float* lsc  = (const float*)d_in[10];
    const float* Wo   = (const float*)d_in[11];
    const float* bo   = (const float*)d_in[12];
    const float* g1   = (const float*)d_in[13];
    const float* be1  = (const float*)d_in[14];
    const float* g2   = (const float*)d_in[15];
    const float* be2  = (const float*)d_in[16];
    const float* g3   = (const float*)d_in[17];
    const float* be3  = (const float*)d_in[18];
    const float* mW1  = (const float*)d_in[19];
    const float* mb1  = (const float*)d_in[20];
    const float* mW2  = (const float*)d_in[21];
    const float* mb2  = (const float*)d_in[22];
    const float* muW1 = (const float*)d_in[23];
    const float* mub1 = (const float*)d_in[24];
    const float* muW2 = (const float*)d_in[25];
    const float* mub2 = (const float*)d_in[26];

    const size_t MB = (size_t)1 << 20;
    char* ws = (char*)d_ws;
    // Timeline-safe layout, 80.5 MiB total (unchanged from round 5)
    u64*            cand   = (u64*)(ws);
    float*          hbuf   = (float*)(ws);
    unsigned short* y1h    = (unsigned short*)(ws);
    unsigned short* y1l    = (unsigned short*)(ws + 16 * MB);
    unsigned short* hnh    = (unsigned short*)(ws + 32 * MB);
    unsigned short* hnl    = (unsigned short*)(ws + 48 * MB);
    u64*            c2c    = (u64*)(ws + 64 * MB);
    unsigned short* w1th   = (unsigned short*)(ws + 72 * MB);
    unsigned short* w1tl   = (unsigned short*)(ws + 74 * MB);
    unsigned short* w2th   = (unsigned short*)(ws + 76 * MB);
    unsigned short* w2tl   = (unsigned short*)(ws + 78 * MB);
    int*            knn    = (int*)(ws + 80 * MB);
    (void)in_sizes; (void)n_in; (void)out_size; (void)ws_size;

    wconv<<<dim3(16, 16, 2), 256, 0, stream>>>(muW1, muW2, w1th, w1tl, w2th, w2tl);
    topk_partial<<<dim3(TT / 256, NC, B_), 256, 0, stream>>>(c1, c2, cand);
    topk_merge1<<<dim3(TT / 64, 8, B_), 64, 0, stream>>>(cand, c2c);
    topk_merge2<<<dim3(TT / 64, B_), 64, 0, stream>>>(c2c, knn);
    tok_pe_m<<<dim3(512), 256, 0, stream>>>(x, c1, c2, knn, peW1, peb1, peW2, peb2, g1, be1, hbuf);
    tok_pe_v<<<dim3(512), 256, 0, stream>>>(x, c1, c2, knn, peW1, peb1, peW2, peb2, g1, be1, hbuf);
    tok_attn<<<dim3(512), 256, 0, stream>>>(x, knn, Wq, Wk, Wv, lsc, Wo, bo, g2, be2, hbuf);
    tok_mnh_m<<<dim3(512), 256, 0, stream>>>(hbuf, mW1, mb1, mW2, mb2, g3, be3, hnh, hnl);
    tok_mnh_v<<<dim3(512), 256, 0, stream>>>(hbuf, mW1, mb1, mW2, mb2, g3, be3, hnh, hnl);
    gemm_split<1><<<dim3(8, 64), 256, 0, stream>>>(hnh, hnl, w1th, w1tl, mub1,
                                                   y1h, y1l, (float*)nullptr, 8192, 1024, 1024);
    gemm_split<0><<<dim3(8, 64), 256, 0, stream>>>(y1h, y1l, w2th, w2tl, mub2,
                                                   (unsigned short*)nullptr, (unsigned short*)nullptr,
                                                   (float*)d_out, 8192, 1024, 1024);
}